// Round 2
// baseline (129.748 us; speedup 1.0000x reference)
//
#include <hip/hip_runtime.h>
#include <hip/hip_bf16.h>

// ConvDeepSet round 8: kill the LDS pipe.
//  Round-7 postmortem: LDS issue throughput (~100k CU-cycles of slab DMA
//  writes + frag ds_reads) was the wall, not occupancy. co per-XCD footprint
//  is only 512 KB (2 pinned batches) -> fully L2-resident.
//  - B-frags read DIRECTLY global->VGPR (dwordx4, 256B segments, L2 hits).
//  - sxa/sxb read global too (16 lanes share each 32B -> 1-2 lines/load).
//  - 32 m/wave (2 A-frags per B-read) to halve L2 volume vs 16 m: 0.5 GB
//    total = 64 MB/XCD ~= 15 us at per-XCD L2 BW.
//  - ZERO __syncthreads in main: no slab, vstage is same-wave, W0/bias read
//    from global in epilogue, exp2(-y^2) row factor via wave shuffle.
//  - depth-1 register double-buffer on the kstep loop (loads issue first,
//    compiler emits counted vmcnt).

#define N_CTX 2048
#define BATCH 16
#define M_TGT 4096
#define COUT  64
#define RDIM  128

#define WS_CO_BYTES (N_CTX * BATCH * COUT * 2)          // 4 MB
#define WS_SXA_OFF  WS_CO_BYTES                         // 128 KB fp32 (2*sx)
#define WS_SXB_OFF  (WS_SXA_OFF + N_CTX * BATCH * 4)    // 128 KB fp32 (-sx^2)
#define WS_WT_OFF   (WS_SXB_OFF + N_CTX * BATCH * 4)    // 16 KB bf16

#define SSCALE 0.8493222f   // sqrt(0.5 * log2(e))

typedef __attribute__((ext_vector_type(8)))  short        bf16x8;
typedef __attribute__((ext_vector_type(4)))  float        floatx4;
typedef __attribute__((ext_vector_type(4)))  unsigned int uint4v;

#if __has_builtin(__builtin_amdgcn_exp2f)
#define EXP2F __builtin_amdgcn_exp2f
#else
#define EXP2F exp2f
#endif

static __device__ __forceinline__ unsigned int pack_bf16(float lo, float hi) {
    __hip_bfloat162 h = __float22bfloat162_rn(make_float2(lo, hi));
    return *reinterpret_cast<unsigned int*>(&h);
}
static __device__ __forceinline__ unsigned short f2bf(float f) {
    __hip_bfloat16 h = __float2bfloat16(f);
    return *reinterpret_cast<unsigned short*>(&h);
}

__global__ __launch_bounds__(256)
void convdeepset_prep(const float* __restrict__ ci, const float* __restrict__ co,
                      const float* __restrict__ ls, const float* __restrict__ W,
                      unsigned char* __restrict__ ws)
{
    unsigned short* cow = (unsigned short*)ws;
    float*          sxa = (float*)(ws + WS_SXA_OFF);
    float*          sxb = (float*)(ws + WS_SXB_OFF);
    unsigned short* wt  = (unsigned short*)(ws + WS_WT_OFF);
    const int blk = blockIdx.x, tid = threadIdx.x;

    if (blk < 1024) {
        // group = (bb, nblk of 8 n); lane = c. Reads coalesced (256B/row),
        // writes fully coalesced dwordx4.
        const int g    = blk * 4 + (tid >> 6);
        const int bb   = g & 15;
        const int nblk = g >> 4;           // 0..255
        const int c    = tid & 63;
        const float* rp = co + ((size_t)nblk * 8 * BATCH + bb) * COUT + c;
        unsigned int u[4];
#pragma unroll
        for (int j = 0; j < 4; ++j) {
            const float f0 = rp[(size_t)(2 * j)     * BATCH * COUT];
            const float f1 = rp[(size_t)(2 * j + 1) * BATCH * COUT];
            u[j] = pack_bf16(f0, f1);
        }
        *(uint4v*)&cow[(size_t)bb * 131072 + nblk * 512 + c * 8] = *(uint4v*)u;
    } else if (blk < 1152) {
        const int f = (blk - 1024) * 256 + tid;   // 0..32767
        const int n = f & 2047, bb = f >> 11;
        const float s = SSCALE / ls[0];
        const float v = s * ci[(size_t)n * BATCH + bb];
        sxa[bb * 2048 + n] = v + v;     // 2*sx
        sxb[bb * 2048 + n] = -v * v;    // -sx^2
    } else {
        for (int f = tid; f < 8192; f += 256) {
            const int cp = f & 7, r = (f >> 3) & 127, ch = f >> 10;
            wt[ch * 1024 + r * 8 + cp] = f2bf(W[r * 65 + 1 + ch * 8 + cp]);
        }
    }
}

struct Slot {
    bf16x8  c0, c1, c2, c3;
    floatx4 xa0, xa1, xb0, xb1;
};

__global__ __launch_bounds__(256)
void convdeepset_main(const float* __restrict__ ti, const float* __restrict__ ls,
                      const float* __restrict__ W,  const float* __restrict__ bias,
                      const unsigned char* __restrict__ ws, float* __restrict__ out)
{
    __shared__ unsigned short vstage[4][2][1024]; // 16 KB, same-wave only

    const int tid  = threadIdx.x;
    const int lane = tid & 63;
    const int wv   = tid >> 6;        // 0..3
    const int g2   = lane >> 4;       // MFMA k-group 0..3
    const int l15  = lane & 15;

    // XCD swizzle: 2 batches pinned per XCD (round-robin dispatch by blk&7)
    const int xcd = blockIdx.x & 7;
    const int i   = blockIdx.x >> 3;  // 0..63
    const int b   = xcd * 2 + (i & 1);
    const int mt  = i >> 1;           // 0..31
    const int m0  = mt * 128 + wv * 32;

    const float s   = SSCALE / ls[0];
    const float sy0 = s * ti[(size_t)(m0 + l15) * BATCH + b];
    const float sy1 = s * ti[(size_t)(m0 + 16 + l15) * BATCH + b];

    const unsigned short* cowb = (const unsigned short*)ws + (size_t)b * 131072;
    const float* sxa = (const float*)(ws + WS_SXA_OFF) + b * N_CTX;
    const float* sxb = (const float*)(ws + WS_SXB_OFF) + b * N_CTX;

    const short onebf = (short)0x3F80;
    bf16x8 ones;
#pragma unroll
    for (int j = 0; j < 8; ++j) ones[j] = onebf;

    floatx4 acc0[4], acc1[4], accd0, accd1;
#pragma unroll
    for (int q = 0; q < 4; ++q)
#pragma unroll
        for (int e = 0; e < 4; ++e) { acc0[q][e] = 0.0f; acc1[q][e] = 0.0f; }
#pragma unroll
    for (int e = 0; e < 4; ++e) { accd0[e] = 0.0f; accd1[e] = 0.0f; }

    auto loadk = [&](Slot& S, int k) {
        const unsigned short* bp = cowb + ((k * 4 + g2) << 9) + l15 * 8;
        S.c0 = *(const bf16x8*)(bp);
        S.c1 = *(const bf16x8*)(bp + 128);
        S.c2 = *(const bf16x8*)(bp + 256);
        S.c3 = *(const bf16x8*)(bp + 384);
        const float* ap  = sxa + k * 32 + g2 * 8;
        const float* bpx = sxb + k * 32 + g2 * 8;
        S.xa0 = *(const floatx4*)(ap);
        S.xa1 = *(const floatx4*)(ap + 4);
        S.xb0 = *(const floatx4*)(bpx);
        S.xb1 = *(const floatx4*)(bpx + 4);
    };

    auto compute = [&](const Slot& S) {
        // arg = 2*sx*sy - sx^2   (the -sy^2 term folds into the epilogue)
        const floatx4 a00 = S.xa0 * sy0 + S.xb0;
        const floatx4 a01 = S.xa1 * sy0 + S.xb1;
        const floatx4 a10 = S.xa0 * sy1 + S.xb0;
        const floatx4 a11 = S.xa1 * sy1 + S.xb1;
        float kv0[8], kv1[8];
        kv0[0] = EXP2F(a00.x); kv0[1] = EXP2F(a00.y);
        kv0[2] = EXP2F(a00.z); kv0[3] = EXP2F(a00.w);
        kv0[4] = EXP2F(a01.x); kv0[5] = EXP2F(a01.y);
        kv0[6] = EXP2F(a01.z); kv0[7] = EXP2F(a01.w);
        kv1[0] = EXP2F(a10.x); kv1[1] = EXP2F(a10.y);
        kv1[2] = EXP2F(a10.z); kv1[3] = EXP2F(a10.w);
        kv1[4] = EXP2F(a11.x); kv1[5] = EXP2F(a11.y);
        kv1[6] = EXP2F(a11.z); kv1[7] = EXP2F(a11.w);
        uint4v aw0, aw1;
#pragma unroll
        for (int q = 0; q < 4; ++q) {
            aw0[q] = pack_bf16(kv0[2 * q], kv0[2 * q + 1]);
            aw1[q] = pack_bf16(kv1[2 * q], kv1[2 * q + 1]);
        }
        const bf16x8 av0 = __builtin_bit_cast(bf16x8, aw0);
        const bf16x8 av1 = __builtin_bit_cast(bf16x8, aw1);
        acc0[0] = __builtin_amdgcn_mfma_f32_16x16x32_bf16(av0, S.c0, acc0[0], 0, 0, 0);
        acc0[1] = __builtin_amdgcn_mfma_f32_16x16x32_bf16(av0, S.c1, acc0[1], 0, 0, 0);
        acc0[2] = __builtin_amdgcn_mfma_f32_16x16x32_bf16(av0, S.c2, acc0[2], 0, 0, 0);
        acc0[3] = __builtin_amdgcn_mfma_f32_16x16x32_bf16(av0, S.c3, acc0[3], 0, 0, 0);
        accd0   = __builtin_amdgcn_mfma_f32_16x16x32_bf16(av0, ones, accd0, 0, 0, 0);
        acc1[0] = __builtin_amdgcn_mfma_f32_16x16x32_bf16(av1, S.c0, acc1[0], 0, 0, 0);
        acc1[1] = __builtin_amdgcn_mfma_f32_16x16x32_bf16(av1, S.c1, acc1[1], 0, 0, 0);
        acc1[2] = __builtin_amdgcn_mfma_f32_16x16x32_bf16(av1, S.c2, acc1[2], 0, 0, 0);
        acc1[3] = __builtin_amdgcn_mfma_f32_16x16x32_bf16(av1, S.c3, acc1[3], 0, 0, 0);
        accd1   = __builtin_amdgcn_mfma_f32_16x16x32_bf16(av1, ones, accd1, 0, 0, 0);
    };

    Slot A, B;
    loadk(A, 0);
    for (int p = 0; p < 64; p += 2) {
        loadk(B, p + 1);                 // p <= 62 so p+1 <= 63 always valid
        compute(A);
        if (p + 2 < 64) loadk(A, p + 2);
        compute(B);
    }

    // ---- per m-tile: stage V (same-wave LDS), project, store ----
    const unsigned short* wtg = (const unsigned short*)(ws + WS_WT_OFF);
    const float sy0sq = sy0 * sy0;
    const float sy1sq = sy1 * sy1;
#pragma unroll
    for (int tile = 0; tile < 2; ++tile) {
        const floatx4* acc  = tile ? acc1 : acc0;
        const floatx4  accd = tile ? accd1 : accd0;
        const float    sysq = tile ? sy1sq : sy0sq;
        // per-row factors: e = exp2(-y^2); dens = accd*e; scale = e/(dens+eps)
        float dt[4], ff[4];
#pragma unroll
        for (int reg = 0; reg < 4; ++reg) {
            const int m   = (lane >> 4) * 4 + reg;  // C/D map row
            const float ysq = __shfl(sysq, m, 64);  // lane m holds row m's y^2
            const float e   = EXP2F(-ysq);
            dt[reg] = accd[reg] * e;
            ff[reg] = e / (dt[reg] + 1e-8f);
        }
        unsigned short* vs = vstage[wv][tile];
#pragma unroll
        for (int reg = 0; reg < 4; ++reg) {
            const int m = (lane >> 4) * 4 + reg;
#pragma unroll
            for (int q = 0; q < 4; ++q) {
                const int c = q * 16 + l15;
                vs[(c >> 3) * 128 + m * 8 + (c & 7)] = f2bf(acc[q][reg]);
            }
        }
        // projection: D[16m][128r] = V @ Wt, same-wave LDS (no barrier)
        floatx4 pacc[8];
#pragma unroll
        for (int rt = 0; rt < 8; ++rt)
#pragma unroll
            for (int e = 0; e < 4; ++e) pacc[rt][e] = 0.0f;
#pragma unroll
        for (int s2 = 0; s2 < 2; ++s2) {
            const int ch = s2 * 4 + g2;
            const bf16x8 avp = *(const bf16x8*)&vs[ch * 128 + l15 * 8];
#pragma unroll
            for (int rt = 0; rt < 8; ++rt) {
                const bf16x8 bvp = *(const bf16x8*)&wtg[ch * 1024 + (rt * 16 + l15) * 8];
                pacc[rt] = __builtin_amdgcn_mfma_f32_16x16x32_bf16(avp, bvp, pacc[rt], 0, 0, 0);
            }
        }
        // epilogue: out = pacc*e/dens + dens*W0 + bias  (W0/bias from L2)
#pragma unroll
        for (int rt = 0; rt < 8; ++rt) {
            const int r = rt * 16 + l15;
            const float w0v = W[r * 65];
            const float bv  = bias[r];
#pragma unroll
            for (int reg = 0; reg < 4; ++reg) {
                const int m = (lane >> 4) * 4 + reg;
                out[((size_t)(m0 + tile * 16 + m) * BATCH + b) * RDIM + r]
                    = pacc[rt][reg] * ff[reg] + dt[reg] * w0v + bv;
            }
        }
    }
}

extern "C" void kernel_launch(void* const* d_in, const int* in_sizes, int n_in,
                              void* d_out, int out_size, void* d_ws, size_t ws_size,
                              hipStream_t stream) {
    const float* ci   = (const float*)d_in[0];  // context_in  (N,B,1)
    const float* co   = (const float*)d_in[1];  // context_out (N,B,64)
    const float* ti   = (const float*)d_in[2];  // target_in   (M,B,1)
    const float* ls   = (const float*)d_in[3];  // lengthscale (1,)
    const float* W    = (const float*)d_in[4];  // (128,65)
    const float* bias = (const float*)d_in[5];  // (128,)
    float* o = (float*)d_out;                   // (M,B,128)
    (void)in_sizes; (void)n_in; (void)out_size; (void)ws_size;

    convdeepset_prep<<<1153, 256, 0, stream>>>(ci, co, ls, W, (unsigned char*)d_ws);
    convdeepset_main<<<512, 256, 0, stream>>>(
        ti, ls, W, bias, (const unsigned char*)d_ws, o);
}

// Round 3
// 128.536 us; speedup vs baseline: 1.0094x; 1.0094x over previous
//
#include <hip/hip_runtime.h>
#include <hip/hip_bf16.h>

// ConvDeepSet round 9: K-split for occupancy without L2-volume or LDS-pipe cost.
//  Round-8 postmortem: direct global->reg at 2 waves/SIMD was latency-bound
//  (depth-1 prefetch can't cover ~200cyc L2 latency); round 7's 4 waves/SIMD
//  was better but paid ~40us of LDS-pipe occupancy for slab staging.
//  - Each wave: 32 m-rows x HALF the context (1024 ctx pts, 32 ksteps).
//    4096 waves = 4 waves/SIMD, grid 1024 = 4 blocks/CU. L2 read volume
//    unchanged vs round 8 (512 MB total, 64 MB/XCD, co L2-resident).
//  - Main loop identical to round 8: zero barriers, B-frags + x-tables
//    direct global->VGPR, depth-1 register double-buffer.
//  - Wave pairs exchange partial acc once via 20KB LDS (one barrier), then
//    each wave finishes ONE 16-row tile (projection + store).

#define N_CTX 2048
#define BATCH 16
#define M_TGT 4096
#define COUT  64
#define RDIM  128

#define WS_CO_BYTES (N_CTX * BATCH * COUT * 2)          // 4 MB
#define WS_SXA_OFF  WS_CO_BYTES                         // 128 KB fp32 (2*sx)
#define WS_SXB_OFF  (WS_SXA_OFF + N_CTX * BATCH * 4)    // 128 KB fp32 (-sx^2)
#define WS_WT_OFF   (WS_SXB_OFF + N_CTX * BATCH * 4)    // 16 KB bf16

#define SSCALE 0.8493222f   // sqrt(0.5 * log2(e))

typedef __attribute__((ext_vector_type(8)))  short        bf16x8;
typedef __attribute__((ext_vector_type(4)))  float        floatx4;
typedef __attribute__((ext_vector_type(4)))  unsigned int uint4v;

#if __has_builtin(__builtin_amdgcn_exp2f)
#define EXP2F __builtin_amdgcn_exp2f
#else
#define EXP2F exp2f
#endif

static __device__ __forceinline__ unsigned int pack_bf16(float lo, float hi) {
    __hip_bfloat162 h = __float22bfloat162_rn(make_float2(lo, hi));
    return *reinterpret_cast<unsigned int*>(&h);
}
static __device__ __forceinline__ unsigned short f2bf(float f) {
    __hip_bfloat16 h = __float2bfloat16(f);
    return *reinterpret_cast<unsigned short*>(&h);
}

__global__ __launch_bounds__(256)
void convdeepset_prep(const float* __restrict__ ci, const float* __restrict__ co,
                      const float* __restrict__ ls, const float* __restrict__ W,
                      unsigned char* __restrict__ ws)
{
    unsigned short* cow = (unsigned short*)ws;
    float*          sxa = (float*)(ws + WS_SXA_OFF);
    float*          sxb = (float*)(ws + WS_SXB_OFF);
    unsigned short* wt  = (unsigned short*)(ws + WS_WT_OFF);
    const int blk = blockIdx.x, tid = threadIdx.x;

    if (blk < 1024) {
        // group = (bb, nblk of 8 n); lane = c. Reads coalesced (256B/row),
        // writes fully coalesced dwordx4.
        const int g    = blk * 4 + (tid >> 6);
        const int bb   = g & 15;
        const int nblk = g >> 4;           // 0..255
        const int c    = tid & 63;
        const float* rp = co + ((size_t)nblk * 8 * BATCH + bb) * COUT + c;
        unsigned int u[4];
#pragma unroll
        for (int j = 0; j < 4; ++j) {
            const float f0 = rp[(size_t)(2 * j)     * BATCH * COUT];
            const float f1 = rp[(size_t)(2 * j + 1) * BATCH * COUT];
            u[j] = pack_bf16(f0, f1);
        }
        *(uint4v*)&cow[(size_t)bb * 131072 + nblk * 512 + c * 8] = *(uint4v*)u;
    } else if (blk < 1152) {
        const int f = (blk - 1024) * 256 + tid;   // 0..32767
        const int n = f & 2047, bb = f >> 11;
        const float s = SSCALE / ls[0];
        const float v = s * ci[(size_t)n * BATCH + bb];
        sxa[bb * 2048 + n] = v + v;     // 2*sx
        sxb[bb * 2048 + n] = -v * v;    // -sx^2
    } else {
        for (int f = tid; f < 8192; f += 256) {
            const int cp = f & 7, r = (f >> 3) & 127, ch = f >> 10;
            wt[ch * 1024 + r * 8 + cp] = f2bf(W[r * 65 + 1 + ch * 8 + cp]);
        }
    }
}

struct Slot {
    bf16x8  c0, c1, c2, c3;
    floatx4 xa0, xa1, xb0, xb1;
};

__global__ __launch_bounds__(256, 4)
void convdeepset_main(const float* __restrict__ ti, const float* __restrict__ ls,
                      const float* __restrict__ W,  const float* __restrict__ bias,
                      const unsigned char* __restrict__ ws, float* __restrict__ out)
{
    __shared__ float xred[4][64][20];             // 20 KB partial-acc exchange
    __shared__ unsigned short vstage[4][1024];    //  8 KB V staging, same-wave

    const int tid  = threadIdx.x;
    const int lane = tid & 63;
    const int wv   = tid >> 6;        // 0..3
    const int g2   = lane >> 4;       // MFMA k-group 0..3
    const int l15  = lane & 15;
    const int wpr  = wv >> 1;         // row-pair 0..1
    const int half = wv & 1;          // ctx half 0..1

    // XCD swizzle: 2 batches pinned per XCD (round-robin dispatch by blk&7)
    const int xcd = blockIdx.x & 7;
    const int i   = blockIdx.x >> 3;  // 0..127
    const int b   = xcd * 2 + (i & 1);
    const int mt  = i >> 1;           // 0..63
    const int m0  = mt * 64 + wpr * 32;   // this wave-pair's 32-row base

    const float s   = SSCALE / ls[0];
    const float sy0 = s * ti[(size_t)(m0 + l15) * BATCH + b];
    const float sy1 = s * ti[(size_t)(m0 + 16 + l15) * BATCH + b];

    // base pointers offset by this wave's ctx half (32 ksteps of 32)
    const unsigned short* cowb = (const unsigned short*)ws
                               + (size_t)b * 131072 + (size_t)half * 65536;
    const float* sxa = (const float*)(ws + WS_SXA_OFF) + b * N_CTX + half * 1024;
    const float* sxb = (const float*)(ws + WS_SXB_OFF) + b * N_CTX + half * 1024;

    const short onebf = (short)0x3F80;
    bf16x8 ones;
#pragma unroll
    for (int j = 0; j < 8; ++j) ones[j] = onebf;

    floatx4 acc0[4], acc1[4], accd0, accd1;
#pragma unroll
    for (int q = 0; q < 4; ++q)
#pragma unroll
        for (int e = 0; e < 4; ++e) { acc0[q][e] = 0.0f; acc1[q][e] = 0.0f; }
#pragma unroll
    for (int e = 0; e < 4; ++e) { accd0[e] = 0.0f; accd1[e] = 0.0f; }

    auto loadk = [&](Slot& S, int k) {
        const unsigned short* bp = cowb + ((k * 4 + g2) << 9) + l15 * 8;
        S.c0 = *(const bf16x8*)(bp);
        S.c1 = *(const bf16x8*)(bp + 128);
        S.c2 = *(const bf16x8*)(bp + 256);
        S.c3 = *(const bf16x8*)(bp + 384);
        const float* ap  = sxa + k * 32 + g2 * 8;
        const float* bpx = sxb + k * 32 + g2 * 8;
        S.xa0 = *(const floatx4*)(ap);
        S.xa1 = *(const floatx4*)(ap + 4);
        S.xb0 = *(const floatx4*)(bpx);
        S.xb1 = *(const floatx4*)(bpx + 4);
    };

    auto compute = [&](const Slot& S) {
        // arg = 2*sx*sy - sx^2   (the -sy^2 term folds into the epilogue)
        const floatx4 a00 = S.xa0 * sy0 + S.xb0;
        const floatx4 a01 = S.xa1 * sy0 + S.xb1;
        const floatx4 a10 = S.xa0 * sy1 + S.xb0;
        const floatx4 a11 = S.xa1 * sy1 + S.xb1;
        float kv0[8], kv1[8];
        kv0[0] = EXP2F(a00.x); kv0[1] = EXP2F(a00.y);
        kv0[2] = EXP2F(a00.z); kv0[3] = EXP2F(a00.w);
        kv0[4] = EXP2F(a01.x); kv0[5] = EXP2F(a01.y);
        kv0[6] = EXP2F(a01.z); kv0[7] = EXP2F(a01.w);
        kv1[0] = EXP2F(a10.x); kv1[1] = EXP2F(a10.y);
        kv1[2] = EXP2F(a10.z); kv1[3] = EXP2F(a10.w);
        kv1[4] = EXP2F(a11.x); kv1[5] = EXP2F(a11.y);
        kv1[6] = EXP2F(a11.z); kv1[7] = EXP2F(a11.w);
        uint4v aw0, aw1;
#pragma unroll
        for (int q = 0; q < 4; ++q) {
            aw0[q] = pack_bf16(kv0[2 * q], kv0[2 * q + 1]);
            aw1[q] = pack_bf16(kv1[2 * q], kv1[2 * q + 1]);
        }
        const bf16x8 av0 = __builtin_bit_cast(bf16x8, aw0);
        const bf16x8 av1 = __builtin_bit_cast(bf16x8, aw1);
        acc0[0] = __builtin_amdgcn_mfma_f32_16x16x32_bf16(av0, S.c0, acc0[0], 0, 0, 0);
        acc0[1] = __builtin_amdgcn_mfma_f32_16x16x32_bf16(av0, S.c1, acc0[1], 0, 0, 0);
        acc0[2] = __builtin_amdgcn_mfma_f32_16x16x32_bf16(av0, S.c2, acc0[2], 0, 0, 0);
        acc0[3] = __builtin_amdgcn_mfma_f32_16x16x32_bf16(av0, S.c3, acc0[3], 0, 0, 0);
        accd0   = __builtin_amdgcn_mfma_f32_16x16x32_bf16(av0, ones, accd0, 0, 0, 0);
        acc1[0] = __builtin_amdgcn_mfma_f32_16x16x32_bf16(av1, S.c0, acc1[0], 0, 0, 0);
        acc1[1] = __builtin_amdgcn_mfma_f32_16x16x32_bf16(av1, S.c1, acc1[1], 0, 0, 0);
        acc1[2] = __builtin_amdgcn_mfma_f32_16x16x32_bf16(av1, S.c2, acc1[2], 0, 0, 0);
        acc1[3] = __builtin_amdgcn_mfma_f32_16x16x32_bf16(av1, S.c3, acc1[3], 0, 0, 0);
        accd1   = __builtin_amdgcn_mfma_f32_16x16x32_bf16(av1, ones, accd1, 0, 0, 0);
    };

    Slot A, B;
    loadk(A, 0);
    for (int p = 0; p < 32; p += 2) {
        loadk(B, p + 1);                 // p <= 30 so p+1 <= 31 always valid
        compute(A);
        if (p + 2 < 32) loadk(A, p + 2);
        compute(B);
    }

    // ---- exchange partials across the ctx-half pair (one barrier) ----
    {
        float* xw = &xred[wv][lane][0];
        const floatx4* wacc = half ? acc0 : acc1;   // the tile we give away
        const floatx4  wd   = half ? accd0 : accd1;
#pragma unroll
        for (int q = 0; q < 4; ++q) *(floatx4*)&xw[q * 4] = wacc[q];
        *(floatx4*)&xw[16] = wd;
    }
    __syncthreads();
    floatx4  facc[4];
    floatx4  faccd;
    {
        const float* xr = &xred[wv ^ 1][lane][0];   // partner wave
        const floatx4* kacc = half ? acc1 : acc0;   // the tile we keep
        const floatx4  kd   = half ? accd1 : accd0;
#pragma unroll
        for (int q = 0; q < 4; ++q) facc[q] = kacc[q] + *(const floatx4*)&xr[q * 4];
        faccd = kd + *(const floatx4*)&xr[16];
    }

    // ---- epilogue: this wave owns ONE 16-row tile (rows m0 + half*16 ..) ----
    const unsigned short* wtg = (const unsigned short*)(ws + WS_WT_OFF);
    const float sysq = half ? sy1 * sy1 : sy0 * sy0;
    const int   mrow = m0 + half * 16;

    // per-row factors: e = exp2(-y^2); dens = accd*e; scale = e/(dens+eps)
    float dt[4], ff[4];
#pragma unroll
    for (int reg = 0; reg < 4; ++reg) {
        const int m   = (lane >> 4) * 4 + reg;   // C/D map row
        const float ysq = __shfl(sysq, m, 64);   // lane m holds row m's y^2
        const float e   = EXP2F(-ysq);
        dt[reg] = faccd[reg] * e;
        ff[reg] = e / (dt[reg] + 1e-8f);
    }
    unsigned short* vs = vstage[wv];
#pragma unroll
    for (int reg = 0; reg < 4; ++reg) {
        const int m = (lane >> 4) * 4 + reg;
#pragma unroll
        for (int q = 0; q < 4; ++q) {
            const int c = q * 16 + l15;
            vs[(c >> 3) * 128 + m * 8 + (c & 7)] = f2bf(facc[q][reg]);
        }
    }
    // projection: D[16m][128r] = V @ Wt, same-wave LDS (no barrier)
    floatx4 pacc[8];
#pragma unroll
    for (int rt = 0; rt < 8; ++rt)
#pragma unroll
        for (int e = 0; e < 4; ++e) pacc[rt][e] = 0.0f;
#pragma unroll
    for (int s2 = 0; s2 < 2; ++s2) {
        const int ch = s2 * 4 + g2;
        const bf16x8 avp = *(const bf16x8*)&vs[ch * 128 + l15 * 8];
#pragma unroll
        for (int rt = 0; rt < 8; ++rt) {
            const bf16x8 bvp = *(const bf16x8*)&wtg[ch * 1024 + (rt * 16 + l15) * 8];
            pacc[rt] = __builtin_amdgcn_mfma_f32_16x16x32_bf16(avp, bvp, pacc[rt], 0, 0, 0);
        }
    }
    // out = pacc*e/dens + dens*W0 + bias  (W0/bias from L2)
#pragma unroll
    for (int rt = 0; rt < 8; ++rt) {
        const int r = rt * 16 + l15;
        const float w0v = W[r * 65];
        const float bv  = bias[r];
#pragma unroll
        for (int reg = 0; reg < 4; ++reg) {
            const int m = (lane >> 4) * 4 + reg;
            out[((size_t)(mrow + m) * BATCH + b) * RDIM + r]
                = pacc[rt][reg] * ff[reg] + dt[reg] * w0v + bv;
        }
    }
}

extern "C" void kernel_launch(void* const* d_in, const int* in_sizes, int n_in,
                              void* d_out, int out_size, void* d_ws, size_t ws_size,
                              hipStream_t stream) {
    const float* ci   = (const float*)d_in[0];  // context_in  (N,B,1)
    const float* co   = (const float*)d_in[1];  // context_out (N,B,64)
    const float* ti   = (const float*)d_in[2];  // target_in   (M,B,1)
    const float* ls   = (const float*)d_in[3];  // lengthscale (1,)
    const float* W    = (const float*)d_in[4];  // (128,65)
    const float* bias = (const float*)d_in[5];  // (128,)
    float* o = (float*)d_out;                   // (M,B,128)
    (void)in_sizes; (void)n_in; (void)out_size; (void)ws_size;

    convdeepset_prep<<<1153, 256, 0, stream>>>(ci, co, ls, W, (unsigned char*)d_ws);
    convdeepset_main<<<1024, 256, 0, stream>>>(
        ti, ls, W, bias, (const unsigned char*)d_ws, o);
}

// Round 4
// 116.764 us; speedup vs baseline: 1.1112x; 1.1008x over previous
//
#include <hip/hip_runtime.h>
#include <hip/hip_bf16.h>

// ConvDeepSet round 10: TA-pipe attack via R=4 row amortization + pipe split.
//  Rounds 8/9 postmortem: identical dur at 2x occupancy, per-CU VMEM instr
//  count invariant -> vector-memory INSTRUCTION throughput (TA) is the wall
//  (~32cy per 1KB dwordx4 wave-load). Round 7 = same story on the LDS pipe.
//  - R=4: 64 m-rows/wave -> 4 B-frag loads feed 20 MFMAs; per-CU big-TA
//    instrs halve to ~1024 (~14us).
//  - x-tables staged once into block LDS (16KB); per-kstep x reads become
//    ds_read_b128 on the otherwise-idle LDS pipe (~5us).
//  - K-split=2: wave pair (same 64 rows, ctx halves) exchanges 2 of 4 tiles
//    through LDS; epilogue 2 tiles (32 rows) per wave.
//  - All acc[] indexing branched on wave-uniform `half` (no runtime-indexed
//    register arrays -> no scratch).

#define N_CTX 2048
#define BATCH 16
#define M_TGT 4096
#define COUT  64
#define RDIM  128

#define WS_CO_BYTES (N_CTX * BATCH * COUT * 2)          // 4 MB
#define WS_SXA_OFF  WS_CO_BYTES                         // 128 KB fp32 (2*sx)
#define WS_SXB_OFF  (WS_SXA_OFF + N_CTX * BATCH * 4)    // 128 KB fp32 (-sx^2)
#define WS_WT_OFF   (WS_SXB_OFF + N_CTX * BATCH * 4)    // 16 KB bf16

#define SSCALE 0.8493222f   // sqrt(0.5 * log2(e))

typedef __attribute__((ext_vector_type(8)))  short        bf16x8;
typedef __attribute__((ext_vector_type(4)))  float        floatx4;
typedef __attribute__((ext_vector_type(4)))  unsigned int uint4v;

#if __has_builtin(__builtin_amdgcn_exp2f)
#define EXP2F __builtin_amdgcn_exp2f
#else
#define EXP2F exp2f
#endif

static __device__ __forceinline__ unsigned int pack_bf16(float lo, float hi) {
    __hip_bfloat162 h = __float22bfloat162_rn(make_float2(lo, hi));
    return *reinterpret_cast<unsigned int*>(&h);
}
static __device__ __forceinline__ unsigned short f2bf(float f) {
    __hip_bfloat16 h = __float2bfloat16(f);
    return *reinterpret_cast<unsigned short*>(&h);
}

__global__ __launch_bounds__(256)
void convdeepset_prep(const float* __restrict__ ci, const float* __restrict__ co,
                      const float* __restrict__ ls, const float* __restrict__ W,
                      unsigned char* __restrict__ ws)
{
    unsigned short* cow = (unsigned short*)ws;
    float*          sxa = (float*)(ws + WS_SXA_OFF);
    float*          sxb = (float*)(ws + WS_SXB_OFF);
    unsigned short* wt  = (unsigned short*)(ws + WS_WT_OFF);
    const int blk = blockIdx.x, tid = threadIdx.x;

    if (blk < 1024) {
        const int g    = blk * 4 + (tid >> 6);
        const int bb   = g & 15;
        const int nblk = g >> 4;           // 0..255
        const int c    = tid & 63;
        const float* rp = co + ((size_t)nblk * 8 * BATCH + bb) * COUT + c;
        unsigned int u[4];
#pragma unroll
        for (int j = 0; j < 4; ++j) {
            const float f0 = rp[(size_t)(2 * j)     * BATCH * COUT];
            const float f1 = rp[(size_t)(2 * j + 1) * BATCH * COUT];
            u[j] = pack_bf16(f0, f1);
        }
        *(uint4v*)&cow[(size_t)bb * 131072 + nblk * 512 + c * 8] = *(uint4v*)u;
    } else if (blk < 1152) {
        const int f = (blk - 1024) * 256 + tid;   // 0..32767
        const int n = f & 2047, bb = f >> 11;
        const float s = SSCALE / ls[0];
        const float v = s * ci[(size_t)n * BATCH + bb];
        sxa[bb * 2048 + n] = v + v;     // 2*sx
        sxb[bb * 2048 + n] = -v * v;    // -sx^2
    } else {
        for (int f = tid; f < 8192; f += 256) {
            const int cp = f & 7, r = (f >> 3) & 127, ch = f >> 10;
            wt[ch * 1024 + r * 8 + cp] = f2bf(W[r * 65 + 1 + ch * 8 + cp]);
        }
    }
}

struct Slot {
    bf16x8  c0, c1, c2, c3;
    floatx4 xa0, xa1, xb0, xb1;
};

__global__ __launch_bounds__(256, 2)
void convdeepset_main(const float* __restrict__ ti, const float* __restrict__ ls,
                      const float* __restrict__ W,  const float* __restrict__ bias,
                      const unsigned char* __restrict__ ws, float* __restrict__ out)
{
    __shared__ float sxal[N_CTX];                 //  8 KB: 2*sx (whole ctx)
    __shared__ float sxbl[N_CTX];                 //  8 KB: -sx^2
    __shared__ float xred[4][64][20];             // 20 KB partial-acc exchange
    __shared__ unsigned short vstage[4][2][1024]; // 16 KB V staging, same-wave
    // 52 KB -> 2 blocks/CU

    const int tid  = threadIdx.x;
    const int lane = tid & 63;
    const int wv   = tid >> 6;        // 0..3
    const int g2   = lane >> 4;       // MFMA k-group 0..3
    const int l15  = lane & 15;
    const int wpr  = wv >> 1;         // team (row group) 0..1
    const int half = wv & 1;          // ctx half 0..1

    // XCD swizzle: 2 batches pinned per XCD
    const int xcd = blockIdx.x & 7;
    const int i   = blockIdx.x >> 3;  // 0..63
    const int b   = xcd * 2 + (i & 1);
    const int mt  = i >> 1;           // 0..31
    const int m0  = mt * 128 + wpr * 64;   // this wave's 64-row base

    // stage x tables (coalesced float4)
    const float4* sag = (const float4*)(ws + WS_SXA_OFF) + b * (N_CTX / 4);
    const float4* sbg = (const float4*)(ws + WS_SXB_OFF) + b * (N_CTX / 4);
    ((float4*)sxal)[tid]       = sag[tid];
    ((float4*)sxal)[tid + 256] = sag[tid + 256];
    ((float4*)sxbl)[tid]       = sbg[tid];
    ((float4*)sxbl)[tid + 256] = sbg[tid + 256];

    const float s = SSCALE / ls[0];
    float syv[4];
#pragma unroll
    for (int t = 0; t < 4; ++t)
        syv[t] = s * ti[(size_t)(m0 + t * 16 + l15) * BATCH + b];

    // B-frag base for this wave's ctx half (32 ksteps of 32 ctx pts)
    const unsigned short* cowb = (const unsigned short*)ws
                               + (size_t)b * 131072 + (size_t)half * 65536;
    const int xoff = half * 1024;     // float offset into sxal/sxbl

    const short onebf = (short)0x3F80;
    bf16x8 ones;
#pragma unroll
    for (int j = 0; j < 8; ++j) ones[j] = onebf;

    floatx4 acc[4][4], accd[4];
#pragma unroll
    for (int t = 0; t < 4; ++t) {
#pragma unroll
        for (int q = 0; q < 4; ++q)
#pragma unroll
            for (int e = 0; e < 4; ++e) acc[t][q][e] = 0.0f;
#pragma unroll
        for (int e = 0; e < 4; ++e) accd[t][e] = 0.0f;
    }

    auto loadk = [&](Slot& S, int k) {
        const unsigned short* bp = cowb + ((k * 4 + g2) << 9) + l15 * 8;
        S.c0 = *(const bf16x8*)(bp);
        S.c1 = *(const bf16x8*)(bp + 128);
        S.c2 = *(const bf16x8*)(bp + 256);
        S.c3 = *(const bf16x8*)(bp + 384);
        const float* ap  = &sxal[xoff + k * 32 + g2 * 8];
        const float* bpx = &sxbl[xoff + k * 32 + g2 * 8];
        S.xa0 = *(const floatx4*)(ap);
        S.xa1 = *(const floatx4*)(ap + 4);
        S.xb0 = *(const floatx4*)(bpx);
        S.xb1 = *(const floatx4*)(bpx + 4);
    };

    auto compute = [&](const Slot& S) {
#pragma unroll
        for (int t = 0; t < 4; ++t) {
            const float sy = syv[t];
            const floatx4 a0 = S.xa0 * sy + S.xb0;
            const floatx4 a1 = S.xa1 * sy + S.xb1;
            float kv[8];
            kv[0] = EXP2F(a0.x); kv[1] = EXP2F(a0.y);
            kv[2] = EXP2F(a0.z); kv[3] = EXP2F(a0.w);
            kv[4] = EXP2F(a1.x); kv[5] = EXP2F(a1.y);
            kv[6] = EXP2F(a1.z); kv[7] = EXP2F(a1.w);
            uint4v aw;
#pragma unroll
            for (int q = 0; q < 4; ++q)
                aw[q] = pack_bf16(kv[2 * q], kv[2 * q + 1]);
            const bf16x8 av = __builtin_bit_cast(bf16x8, aw);
            acc[t][0] = __builtin_amdgcn_mfma_f32_16x16x32_bf16(av, S.c0, acc[t][0], 0, 0, 0);
            acc[t][1] = __builtin_amdgcn_mfma_f32_16x16x32_bf16(av, S.c1, acc[t][1], 0, 0, 0);
            acc[t][2] = __builtin_amdgcn_mfma_f32_16x16x32_bf16(av, S.c2, acc[t][2], 0, 0, 0);
            acc[t][3] = __builtin_amdgcn_mfma_f32_16x16x32_bf16(av, S.c3, acc[t][3], 0, 0, 0);
            accd[t]   = __builtin_amdgcn_mfma_f32_16x16x32_bf16(av, ones, accd[t], 0, 0, 0);
        }
    };

    __syncthreads();   // x tables visible
    Slot A, B;
    loadk(A, 0);
    for (int p = 0; p < 32; p += 2) {
        loadk(B, p + 1);                 // p <= 30 so p+1 <= 31 always valid
        compute(A);
        if (p + 2 < 32) loadk(A, p + 2);
        compute(B);
    }

    // ---- exchange: wave keeps tiles {half*2, half*2+1}, sends the others ----
#pragma unroll
    for (int j = 0; j < 2; ++j) {
        float* xw = &xred[wv][lane][0];
        if (half == 0) {          // send tile 2+j
            *(floatx4*)&xw[0]  = acc[2 + j][0];
            *(floatx4*)&xw[4]  = acc[2 + j][1];
            *(floatx4*)&xw[8]  = acc[2 + j][2];
            *(floatx4*)&xw[12] = acc[2 + j][3];
            *(floatx4*)&xw[16] = accd[2 + j];
        } else {                  // send tile j
            *(floatx4*)&xw[0]  = acc[j][0];
            *(floatx4*)&xw[4]  = acc[j][1];
            *(floatx4*)&xw[8]  = acc[j][2];
            *(floatx4*)&xw[12] = acc[j][3];
            *(floatx4*)&xw[16] = accd[j];
        }
        __syncthreads();
        const float* xr = &xred[wv ^ 1][lane][0];
        if (half == 0) {          // receive tile j
            acc[j][0] += *(const floatx4*)&xr[0];
            acc[j][1] += *(const floatx4*)&xr[4];
            acc[j][2] += *(const floatx4*)&xr[8];
            acc[j][3] += *(const floatx4*)&xr[12];
            accd[j]   += *(const floatx4*)&xr[16];
        } else {                  // receive tile 2+j
            acc[2 + j][0] += *(const floatx4*)&xr[0];
            acc[2 + j][1] += *(const floatx4*)&xr[4];
            acc[2 + j][2] += *(const floatx4*)&xr[8];
            acc[2 + j][3] += *(const floatx4*)&xr[12];
            accd[2 + j]   += *(const floatx4*)&xr[16];
        }
        __syncthreads();
    }

    // ---- epilogue: 2 owned tiles -> stage V, project, store ----
    const unsigned short* wtg = (const unsigned short*)(ws + WS_WT_OFF);

    auto epi = [&](const floatx4 (&a)[4], const floatx4 ad, float syt, int t, int tt) {
        const float sysq = syt * syt;
        const int   mrow = m0 + t * 16;
        float dt[4], ff[4];
#pragma unroll
        for (int reg = 0; reg < 4; ++reg) {
            const int m   = (lane >> 4) * 4 + reg;   // C/D map row
            const float ysq = __shfl(sysq, m, 64);   // lane m holds row m's y^2
            const float e   = EXP2F(-ysq);
            dt[reg] = ad[reg] * e;
            ff[reg] = e / (dt[reg] + 1e-8f);
        }
        unsigned short* vs = vstage[wv][tt];
#pragma unroll
        for (int reg = 0; reg < 4; ++reg) {
            const int m = (lane >> 4) * 4 + reg;
#pragma unroll
            for (int q = 0; q < 4; ++q) {
                const int c = q * 16 + l15;
                vs[(c >> 3) * 128 + m * 8 + (c & 7)] = f2bf(a[q][reg]);
            }
        }
        floatx4 pacc[8];
#pragma unroll
        for (int rt = 0; rt < 8; ++rt)
#pragma unroll
            for (int e = 0; e < 4; ++e) pacc[rt][e] = 0.0f;
#pragma unroll
        for (int s2 = 0; s2 < 2; ++s2) {
            const int ch = s2 * 4 + g2;
            const bf16x8 avp = *(const bf16x8*)&vs[ch * 128 + l15 * 8];
#pragma unroll
            for (int rt = 0; rt < 8; ++rt) {
                const bf16x8 bvp = *(const bf16x8*)&wtg[ch * 1024 + (rt * 16 + l15) * 8];
                pacc[rt] = __builtin_amdgcn_mfma_f32_16x16x32_bf16(avp, bvp, pacc[rt], 0, 0, 0);
            }
        }
#pragma unroll
        for (int rt = 0; rt < 8; ++rt) {
            const int r = rt * 16 + l15;
            const float w0v = W[r * 65];
            const float bv  = bias[r];
#pragma unroll
            for (int reg = 0; reg < 4; ++reg) {
                const int m = (lane >> 4) * 4 + reg;
                out[((size_t)(mrow + m) * BATCH + b) * RDIM + r]
                    = pacc[rt][reg] * ff[reg] + dt[reg] * w0v + bv;
            }
        }
    };

    if (half == 0) {
        epi(acc[0], accd[0], syv[0], 0, 0);
        epi(acc[1], accd[1], syv[1], 1, 1);
    } else {
        epi(acc[2], accd[2], syv[2], 2, 0);
        epi(acc[3], accd[3], syv[3], 3, 1);
    }
}

extern "C" void kernel_launch(void* const* d_in, const int* in_sizes, int n_in,
                              void* d_out, int out_size, void* d_ws, size_t ws_size,
                              hipStream_t stream) {
    const float* ci   = (const float*)d_in[0];  // context_in  (N,B,1)
    const float* co   = (const float*)d_in[1];  // context_out (N,B,64)
    const float* ti   = (const float*)d_in[2];  // target_in   (M,B,1)
    const float* ls   = (const float*)d_in[3];  // lengthscale (1,)
    const float* W    = (const float*)d_in[4];  // (128,65)
    const float* bias = (const float*)d_in[5];  // (128,)
    float* o = (float*)d_out;                   // (M,B,128)
    (void)in_sizes; (void)n_in; (void)out_size; (void)ws_size;

    convdeepset_prep<<<1153, 256, 0, stream>>>(ci, co, ls, W, (unsigned char*)d_ws);
    convdeepset_main<<<512, 256, 0, stream>>>(
        ti, ls, W, bias, (const unsigned char*)d_ws, o);
}